// Round 1
// baseline (2937.857 us; speedup 1.0000x reference)
//
#include <hip/hip_runtime.h>

#define N_NODES 100000
#define N_EDGES 3200000
#define F_IN 64
#define HID 64
#define NOUT 6

// ---------------- degree / dinv ----------------
__global__ __launch_bounds__(256) void k_initdeg(float* __restrict__ deg) {
    int i = blockIdx.x * 256 + threadIdx.x;
    if (i < N_NODES) deg[i] = 1.0f;   // self-loop
}

__global__ __launch_bounds__(256) void k_deg(const int* __restrict__ col, float* __restrict__ deg) {
    int e = blockIdx.x * 256 + threadIdx.x;
    if (e < N_EDGES) unsafeAtomicAdd(&deg[col[e]], 1.0f);
}

__global__ __launch_bounds__(256) void k_dinv(float* __restrict__ deg) {
    int i = blockIdx.x * 256 + threadIdx.x;
    if (i < N_NODES) deg[i] = rsqrtf(deg[i]);   // deg >= 1 always
}

// ---------------- layer 1 GEMM: hs1 = (x @ W1) * dinv ; agg1 = hs1 ----------------
__global__ __launch_bounds__(256) void k_gemm1(const float* __restrict__ x,
                                               const float* __restrict__ W1,
                                               const float* __restrict__ dinv,
                                               float* __restrict__ hs1,
                                               float* __restrict__ agg1) {
    __shared__ float Ws[64 * 64];
    __shared__ float Xs[64 * 65];          // +1 pad: read pattern (n varies, k fixed) spreads banks
    const int tx = threadIdx.x;
    const int nodeBase = blockIdx.x * 64;

    for (int t = tx; t < 64 * 64; t += 256) Ws[t] = W1[t];

    for (int t = tx; t < 64 * 16; t += 256) {        // 64 rows x 16 float4
        int r = t >> 4, c4 = t & 15;
        int g = nodeBase + r;
        float4 v = make_float4(0.f, 0.f, 0.f, 0.f);
        if (g < N_NODES) v = reinterpret_cast<const float4*>(x)[g * 16 + c4];
        float* p = &Xs[r * 65 + c4 * 4];
        p[0] = v.x; p[1] = v.y; p[2] = v.z; p[3] = v.w;
    }
    __syncthreads();

    const int nG = tx >> 4;     // 0..15 -> 4 nodes each
    const int cG = tx & 15;     // 0..15 -> 4 cols each
    float acc[4][4] = {};
    for (int k = 0; k < 64; ++k) {
        float4 w = *reinterpret_cast<const float4*>(&Ws[k * 64 + cG * 4]);
#pragma unroll
        for (int i = 0; i < 4; ++i) {
            float xv = Xs[(nG * 4 + i) * 65 + k];
            acc[i][0] = fmaf(xv, w.x, acc[i][0]);
            acc[i][1] = fmaf(xv, w.y, acc[i][1]);
            acc[i][2] = fmaf(xv, w.z, acc[i][2]);
            acc[i][3] = fmaf(xv, w.w, acc[i][3]);
        }
    }

#pragma unroll
    for (int i = 0; i < 4; ++i) {
        int n = nodeBase + nG * 4 + i;
        if (n < N_NODES) {
            float dv = dinv[n];
            float4 o = make_float4(acc[i][0] * dv, acc[i][1] * dv, acc[i][2] * dv, acc[i][3] * dv);
            reinterpret_cast<float4*>(hs1)[n * 16 + cG] = o;
            reinterpret_cast<float4*>(agg1)[n * 16 + cG] = o;
        }
    }
}

// ---------------- edge scatter, layer 1: agg1[col] += hs1[row] ----------------
__global__ __launch_bounds__(256) void k_scatter1(const int* __restrict__ row,
                                                  const int* __restrict__ col,
                                                  const float* __restrict__ hs1,
                                                  float* __restrict__ agg1) {
    int tid = blockIdx.x * 256 + threadIdx.x;
    int e = tid >> 4, lane = tid & 15;
    if (e >= N_EDGES) return;
    int r = row[e], c = col[e];
    float4 v = reinterpret_cast<const float4*>(hs1)[r * 16 + lane];
    float* dst = agg1 + c * 64 + lane * 4;
    unsafeAtomicAdd(dst + 0, v.x);
    unsafeAtomicAdd(dst + 1, v.y);
    unsafeAtomicAdd(dst + 2, v.z);
    unsafeAtomicAdd(dst + 3, v.w);
}

// ---------------- layer 2 fused: h1 = relu(dinv*agg1 + b1); hs2 = (h1@W2)*dinv; agg2 = hs2 --------
__global__ __launch_bounds__(128) void k_layer2(const float* __restrict__ agg1,
                                                const float* __restrict__ W2,
                                                const float* __restrict__ b1,
                                                const float* __restrict__ dinv,
                                                float* __restrict__ hs2,
                                                float* __restrict__ agg2) {
    __shared__ float W2s[64][8];
    __shared__ float b1s[64];
    __shared__ float Xs[128][65];
    const int tx = threadIdx.x;   // 128
    if (tx < 64) b1s[tx] = b1[tx];
    for (int t = tx; t < 64 * NOUT; t += 128) W2s[t / NOUT][t % NOUT] = W2[t];

    const int nodeBase = blockIdx.x * 128;
    for (int t = tx; t < 128 * 16; t += 128) {
        int r = t >> 4, c4 = t & 15;
        int g = nodeBase + r;
        float4 v = make_float4(0.f, 0.f, 0.f, 0.f);
        if (g < N_NODES) v = reinterpret_cast<const float4*>(agg1)[g * 16 + c4];
        float* p = &Xs[r][c4 * 4];
        p[0] = v.x; p[1] = v.y; p[2] = v.z; p[3] = v.w;
    }
    __syncthreads();

    int n = nodeBase + tx;
    if (n >= N_NODES) return;
    float dv = dinv[n];
    float acc[NOUT] = {};
    for (int k = 0; k < 64; ++k) {
        float hv = fmaxf(fmaf(dv, Xs[tx][k], b1s[k]), 0.f);
#pragma unroll
        for (int j = 0; j < NOUT; ++j) acc[j] = fmaf(hv, W2s[k][j], acc[j]);
    }
    float* o1 = hs2 + n * 8;
    float* o2 = agg2 + n * 8;
#pragma unroll
    for (int j = 0; j < NOUT; ++j) { float v = acc[j] * dv; o1[j] = v; o2[j] = v; }
}

// ---------------- edge scatter, layer 2 ----------------
__global__ __launch_bounds__(256) void k_scatter2(const int* __restrict__ row,
                                                  const int* __restrict__ col,
                                                  const float* __restrict__ hs2,
                                                  float* __restrict__ agg2) {
    int tid = blockIdx.x * 256 + threadIdx.x;
    int e = tid >> 3, lane = tid & 7;
    if (e >= N_EDGES || lane >= NOUT) return;
    int r = row[e], c = col[e];
    unsafeAtomicAdd(agg2 + c * 8 + lane, hs2[r * 8 + lane]);
}

// ---------------- final mean reduction ----------------
__global__ __launch_bounds__(256) void k_reduce1(const float* __restrict__ agg2,
                                                 const float* __restrict__ dinv,
                                                 float* __restrict__ partials) {
    float acc[NOUT] = {};
    for (int n = blockIdx.x * 256 + threadIdx.x; n < N_NODES; n += 256 * 1024) {
        float dv = dinv[n];
        const float* rp = agg2 + n * 8;
#pragma unroll
        for (int j = 0; j < NOUT; ++j) acc[j] += dv * rp[j];
    }
    __shared__ float s[NOUT * 256];
    for (int j = 0; j < NOUT; ++j) s[j * 256 + threadIdx.x] = acc[j];
    __syncthreads();
    for (int off = 128; off > 0; off >>= 1) {
        if (threadIdx.x < off)
            for (int j = 0; j < NOUT; ++j)
                s[j * 256 + threadIdx.x] += s[j * 256 + threadIdx.x + off];
        __syncthreads();
    }
    if (threadIdx.x == 0)
        for (int j = 0; j < NOUT; ++j) partials[blockIdx.x * 8 + j] = s[j * 256];
}

__global__ __launch_bounds__(256) void k_reduce2(const float* __restrict__ partials,
                                                 const float* __restrict__ b2,
                                                 float* __restrict__ out) {
    __shared__ float s[256];
    for (int j = 0; j < NOUT; ++j) {
        float a = 0.f;
        for (int p = threadIdx.x; p < 1024; p += 256) a += partials[p * 8 + j];
        s[threadIdx.x] = a;
        __syncthreads();
        for (int off = 128; off > 0; off >>= 1) {
            if (threadIdx.x < off) s[threadIdx.x] += s[threadIdx.x + off];
            __syncthreads();
        }
        if (threadIdx.x == 0) out[j] = b2[j] + s[0] * (1.0f / N_NODES);
        __syncthreads();
    }
}

extern "C" void kernel_launch(void* const* d_in, const int* in_sizes, int n_in,
                              void* d_out, int out_size, void* d_ws, size_t ws_size,
                              hipStream_t stream) {
    const float* x  = (const float*)d_in[0];
    const int*   ei = (const int*)d_in[1];
    const float* W1 = (const float*)d_in[2];
    const float* b1 = (const float*)d_in[3];
    const float* W2 = (const float*)d_in[4];
    const float* b2 = (const float*)d_in[5];
    float* out = (float*)d_out;

    float* ws       = (float*)d_ws;
    float* dinv     = ws;                        // N
    float* hs1      = dinv + N_NODES;            // N*64
    float* agg1     = hs1 + N_NODES * 64;        // N*64
    float* hs2      = agg1 + N_NODES * 64;       // N*8
    float* agg2     = hs2 + N_NODES * 8;         // N*8
    float* partials = agg2 + N_NODES * 8;        // 1024*8

    const int* row = ei;              // sources
    const int* col = ei + N_EDGES;    // targets

    k_initdeg<<<(N_NODES + 255) / 256, 256, 0, stream>>>(dinv);
    k_deg<<<(N_EDGES + 255) / 256, 256, 0, stream>>>(col, dinv);
    k_dinv<<<(N_NODES + 255) / 256, 256, 0, stream>>>(dinv);

    k_gemm1<<<(N_NODES + 63) / 64, 256, 0, stream>>>(x, W1, dinv, hs1, agg1);
    k_scatter1<<<(N_EDGES * 16 + 255) / 256, 256, 0, stream>>>(row, col, hs1, agg1);
    k_layer2<<<(N_NODES + 127) / 128, 128, 0, stream>>>(agg1, W2, b1, dinv, hs2, agg2);
    k_scatter2<<<(N_EDGES * 8 + 255) / 256, 256, 0, stream>>>(row, col, hs2, agg2);

    k_reduce1<<<1024, 256, 0, stream>>>(agg2, dinv, partials);
    k_reduce2<<<1, 256, 0, stream>>>(partials, b2, out);
}

// Round 2
// 669.338 us; speedup vs baseline: 4.3892x; 4.3892x over previous
//
#include <hip/hip_runtime.h>

#define N_NODES 100000
#define N_EDGES 3200000
#define F_IN 64
#define HID 64
#define NOUT 6

#define SCAN_CHUNK 1024
#define SCAN_NB ((N_NODES + SCAN_CHUNK - 1) / SCAN_CHUNK)   // 98

// ---------------- histogram of targets ----------------
__global__ __launch_bounds__(256) void k_zero(int* __restrict__ counts) {
    int i = blockIdx.x * 256 + threadIdx.x;
    if (i < N_NODES) counts[i] = 0;
}

__global__ __launch_bounds__(256) void k_hist(const int* __restrict__ col, int* __restrict__ counts) {
    int e = blockIdx.x * 256 + threadIdx.x;
    if (e < N_EDGES) atomicAdd(&counts[col[e]], 1);
}

__global__ __launch_bounds__(256) void k_dinv(const int* __restrict__ counts, float* __restrict__ dinv) {
    int i = blockIdx.x * 256 + threadIdx.x;
    if (i < N_NODES) dinv[i] = rsqrtf((float)counts[i] + 1.0f);   // +1 self-loop
}

// ---------------- exclusive scan of counts -> offsets ----------------
__global__ __launch_bounds__(256) void k_scan1(const int* __restrict__ counts,
                                               int* __restrict__ offsets,
                                               int* __restrict__ blockSums) {
    __shared__ int s[256];
    const int t = threadIdx.x;
    const int base = blockIdx.x * SCAN_CHUNK + t * 4;
    int v[4];
#pragma unroll
    for (int k = 0; k < 4; ++k) { int i = base + k; v[k] = (i < N_NODES) ? counts[i] : 0; }
    int mysum = v[0] + v[1] + v[2] + v[3];
    s[t] = mysum;
    __syncthreads();
    for (int off = 1; off < 256; off <<= 1) {
        int u = 0;
        if (t >= off) u = s[t - off];
        __syncthreads();
        if (t >= off) s[t] += u;
        __syncthreads();
    }
    int run = s[t] - mysum;   // exclusive prefix for this thread
#pragma unroll
    for (int k = 0; k < 4; ++k) { int i = base + k; if (i < N_NODES) offsets[i] = run; run += v[k]; }
    if (t == 255) blockSums[blockIdx.x] = s[255];
}

__global__ __launch_bounds__(128) void k_scan2(int* __restrict__ blockSums) {
    __shared__ int s[128];
    const int t = threadIdx.x;
    int orig = (t < SCAN_NB) ? blockSums[t] : 0;
    s[t] = orig;
    __syncthreads();
    for (int off = 1; off < 128; off <<= 1) {
        int u = 0;
        if (t >= off) u = s[t - off];
        __syncthreads();
        if (t >= off) s[t] += u;
        __syncthreads();
    }
    if (t < SCAN_NB) blockSums[t] = s[t] - orig;   // exclusive
}

__global__ __launch_bounds__(256) void k_scan3(int* __restrict__ offsets,
                                               const int* __restrict__ blockSums,
                                               int* __restrict__ cursor) {
    int i = blockIdx.x * 256 + threadIdx.x;
    if (i < N_NODES) {
        int o = offsets[i] + blockSums[i >> 10];
        offsets[i] = o;
        cursor[i] = o;
    }
    if (i == 0) offsets[N_NODES] = N_EDGES;
}

// ---------------- rank-scatter edges into target-sorted order ----------------
__global__ __launch_bounds__(256) void k_sort(const int* __restrict__ row, const int* __restrict__ col,
                                              int* __restrict__ cursor, int* __restrict__ sorted_row) {
    int e = blockIdx.x * 256 + threadIdx.x;
    if (e >= N_EDGES) return;
    int pos = atomicAdd(&cursor[col[e]], 1);
    sorted_row[pos] = row[e];
}

// ---------------- layer 1 GEMM: hs1 = (x @ W1) * dinv ----------------
__global__ __launch_bounds__(256) void k_gemm1(const float* __restrict__ x,
                                               const float* __restrict__ W1,
                                               const float* __restrict__ dinv,
                                               float* __restrict__ hs1) {
    __shared__ float Ws[64 * 64];
    __shared__ float Xs[64 * 65];
    const int tx = threadIdx.x;
    const int nodeBase = blockIdx.x * 64;

    for (int t = tx; t < 64 * 64; t += 256) Ws[t] = W1[t];

    for (int t = tx; t < 64 * 16; t += 256) {
        int r = t >> 4, c4 = t & 15;
        int g = nodeBase + r;
        float4 v = make_float4(0.f, 0.f, 0.f, 0.f);
        if (g < N_NODES) v = reinterpret_cast<const float4*>(x)[g * 16 + c4];
        float* p = &Xs[r * 65 + c4 * 4];
        p[0] = v.x; p[1] = v.y; p[2] = v.z; p[3] = v.w;
    }
    __syncthreads();

    const int nG = tx >> 4;
    const int cG = tx & 15;
    float acc[4][4] = {};
    for (int k = 0; k < 64; ++k) {
        float4 w = *reinterpret_cast<const float4*>(&Ws[k * 64 + cG * 4]);
#pragma unroll
        for (int i = 0; i < 4; ++i) {
            float xv = Xs[(nG * 4 + i) * 65 + k];
            acc[i][0] = fmaf(xv, w.x, acc[i][0]);
            acc[i][1] = fmaf(xv, w.y, acc[i][1]);
            acc[i][2] = fmaf(xv, w.z, acc[i][2]);
            acc[i][3] = fmaf(xv, w.w, acc[i][3]);
        }
    }

#pragma unroll
    for (int i = 0; i < 4; ++i) {
        int n = nodeBase + nG * 4 + i;
        if (n < N_NODES) {
            float dv = dinv[n];
            float4 o = make_float4(acc[i][0] * dv, acc[i][1] * dv, acc[i][2] * dv, acc[i][3] * dv);
            reinterpret_cast<float4*>(hs1)[n * 16 + cG] = o;
        }
    }
}

// ---------------- segment-sum layer 1: agg1[c] = hs1[c] + sum over sorted sources ----------------
__global__ __launch_bounds__(256) void k_agg1(const int* __restrict__ offsets,
                                              const int* __restrict__ sorted_row,
                                              const float* __restrict__ hs1,
                                              float* __restrict__ agg1) {
    int wid = (blockIdx.x * 256 + threadIdx.x) >> 6;   // one wave per target node
    int lane = threadIdx.x & 63;                       // lane = feature channel
    if (wid >= N_NODES) return;
    int s = offsets[wid], e = offsets[wid + 1];
    float acc = hs1[wid * 64 + lane];                  // self-loop term
    int j = s;
    for (; j + 1 < e; j += 2) {                        // 2 independent gathers per iter
        int r0 = sorted_row[j], r1 = sorted_row[j + 1];
        float a = hs1[r0 * 64 + lane];
        float b = hs1[r1 * 64 + lane];
        acc += a; acc += b;
    }
    if (j < e) acc += hs1[sorted_row[j] * 64 + lane];
    agg1[wid * 64 + lane] = acc;
}

// ---------------- layer 2 fused: h1 = relu(dinv*agg1 + b1); hs2 = (h1@W2)*dinv ----------------
__global__ __launch_bounds__(128) void k_layer2(const float* __restrict__ agg1,
                                                const float* __restrict__ W2,
                                                const float* __restrict__ b1,
                                                const float* __restrict__ dinv,
                                                float* __restrict__ hs2) {
    __shared__ float W2s[64][8];
    __shared__ float b1s[64];
    __shared__ float Xs[128][65];
    const int tx = threadIdx.x;
    if (tx < 64) b1s[tx] = b1[tx];
    for (int t = tx; t < 64 * NOUT; t += 128) W2s[t / NOUT][t % NOUT] = W2[t];

    const int nodeBase = blockIdx.x * 128;
    for (int t = tx; t < 128 * 16; t += 128) {
        int r = t >> 4, c4 = t & 15;
        int g = nodeBase + r;
        float4 v = make_float4(0.f, 0.f, 0.f, 0.f);
        if (g < N_NODES) v = reinterpret_cast<const float4*>(agg1)[g * 16 + c4];
        float* p = &Xs[r][c4 * 4];
        p[0] = v.x; p[1] = v.y; p[2] = v.z; p[3] = v.w;
    }
    __syncthreads();

    int n = nodeBase + tx;
    if (n >= N_NODES) return;
    float dv = dinv[n];
    float acc[NOUT] = {};
    for (int k = 0; k < 64; ++k) {
        float hv = fmaxf(fmaf(dv, Xs[tx][k], b1s[k]), 0.f);
#pragma unroll
        for (int j = 0; j < NOUT; ++j) acc[j] = fmaf(hv, W2s[k][j], acc[j]);
    }
    float* o1 = hs2 + n * 8;
#pragma unroll
    for (int j = 0; j < NOUT; ++j) o1[j] = acc[j] * dv;
    o1[6] = 0.f; o1[7] = 0.f;   // padding channels must be clean (read by k_agg2)
}

// ---------------- segment-sum layer 2: wave per node, 8 edges x 8 chans at once ----------------
__global__ __launch_bounds__(256) void k_agg2(const int* __restrict__ offsets,
                                              const int* __restrict__ sorted_row,
                                              const float* __restrict__ hs2,
                                              float* __restrict__ agg2) {
    int wid = (blockIdx.x * 256 + threadIdx.x) >> 6;
    int lane = threadIdx.x & 63;
    if (wid >= N_NODES) return;
    int chan = lane & 7, slot = lane >> 3;   // 8 edge-slots x 8 channels
    int s = offsets[wid], e = offsets[wid + 1];
    float acc = 0.f;
    for (int j = s + slot; j < e; j += 8) {
        int r = sorted_row[j];
        acc += hs2[r * 8 + chan];
    }
    acc += __shfl_xor(acc, 8, 64);
    acc += __shfl_xor(acc, 16, 64);
    acc += __shfl_xor(acc, 32, 64);
    if (lane < 8) agg2[wid * 8 + lane] = hs2[wid * 8 + lane] + acc;   // + self
}

// ---------------- final mean reduction ----------------
__global__ __launch_bounds__(256) void k_reduce1(const float* __restrict__ agg2,
                                                 const float* __restrict__ dinv,
                                                 float* __restrict__ partials) {
    float acc[NOUT] = {};
    for (int n = blockIdx.x * 256 + threadIdx.x; n < N_NODES; n += 256 * 1024) {
        float dv = dinv[n];
        const float* rp = agg2 + n * 8;
#pragma unroll
        for (int j = 0; j < NOUT; ++j) acc[j] += dv * rp[j];
    }
    __shared__ float s[NOUT * 256];
    for (int j = 0; j < NOUT; ++j) s[j * 256 + threadIdx.x] = acc[j];
    __syncthreads();
    for (int off = 128; off > 0; off >>= 1) {
        if (threadIdx.x < off)
            for (int j = 0; j < NOUT; ++j)
                s[j * 256 + threadIdx.x] += s[j * 256 + threadIdx.x + off];
        __syncthreads();
    }
    if (threadIdx.x == 0)
        for (int j = 0; j < NOUT; ++j) partials[blockIdx.x * 8 + j] = s[j * 256];
}

__global__ __launch_bounds__(256) void k_reduce2(const float* __restrict__ partials,
                                                 const float* __restrict__ b2,
                                                 float* __restrict__ out) {
    __shared__ float s[256];
    for (int j = 0; j < NOUT; ++j) {
        float a = 0.f;
        for (int p = threadIdx.x; p < 1024; p += 256) a += partials[p * 8 + j];
        s[threadIdx.x] = a;
        __syncthreads();
        for (int off = 128; off > 0; off >>= 1) {
            if (threadIdx.x < off) s[threadIdx.x] += s[threadIdx.x + off];
            __syncthreads();
        }
        if (threadIdx.x == 0) out[j] = b2[j] + s[0] * (1.0f / N_NODES);
        __syncthreads();
    }
}

extern "C" void kernel_launch(void* const* d_in, const int* in_sizes, int n_in,
                              void* d_out, int out_size, void* d_ws, size_t ws_size,
                              hipStream_t stream) {
    const float* x  = (const float*)d_in[0];
    const int*   ei = (const int*)d_in[1];
    const float* W1 = (const float*)d_in[2];
    const float* b1 = (const float*)d_in[3];
    const float* W2 = (const float*)d_in[4];
    const float* b2 = (const float*)d_in[5];
    float* out = (float*)d_out;

    // float region first (keeps float4 targets 16B-aligned), then int region
    float* fw       = (float*)d_ws;
    float* hs1      = fw;                          // N*64
    float* agg1     = hs1 + N_NODES * 64;          // N*64
    float* hs2      = agg1 + N_NODES * 64;         // N*8
    float* agg2     = hs2 + N_NODES * 8;           // N*8
    float* dinv     = agg2 + N_NODES * 8;          // N
    float* partials = dinv + N_NODES;              // 1024*8
    int*   iw       = (int*)(partials + 1024 * 8);
    int*   counts   = iw;                          // N
    int*   offsets  = counts + N_NODES;            // N+1
    int*   cursor   = offsets + N_NODES + 1;       // N
    int*   blockSums= cursor + N_NODES;            // 128
    int*   sorted_row = blockSums + 128;           // E

    const int* row = ei;              // sources
    const int* col = ei + N_EDGES;    // targets

    const int gbN = (N_NODES + 255) / 256;
    const int gbE = (N_EDGES + 255) / 256;

    // build CSR-by-target
    k_zero<<<gbN, 256, 0, stream>>>(counts);
    k_hist<<<gbE, 256, 0, stream>>>(col, counts);
    k_dinv<<<gbN, 256, 0, stream>>>(counts, dinv);
    k_scan1<<<SCAN_NB, 256, 0, stream>>>(counts, offsets, blockSums);
    k_scan2<<<1, 128, 0, stream>>>(blockSums);
    k_scan3<<<gbN, 256, 0, stream>>>(offsets, blockSums, cursor);
    k_sort<<<gbE, 256, 0, stream>>>(row, col, cursor, sorted_row);

    // layer 1
    k_gemm1<<<(N_NODES + 63) / 64, 256, 0, stream>>>(x, W1, dinv, hs1);
    k_agg1<<<(N_NODES * 64 + 255) / 256, 256, 0, stream>>>(offsets, sorted_row, hs1, agg1);

    // layer 2
    k_layer2<<<(N_NODES + 127) / 128, 128, 0, stream>>>(agg1, W2, b1, dinv, hs2);
    k_agg2<<<(N_NODES * 64 + 255) / 256, 256, 0, stream>>>(offsets, sorted_row, hs2, agg2);

    // mean
    k_reduce1<<<1024, 256, 0, stream>>>(agg2, dinv, partials);
    k_reduce2<<<1, 256, 0, stream>>>(partials, b2, out);
}